// Round 7
// baseline (133.437 us; speedup 1.0000x reference)
//
#include <hip/hip_runtime.h>
#include <hip/hip_bf16.h>
#include <math.h>

#define D 32
#define CAP 64      // bucket capacity (mid path up to CAP, full-scan beyond)
#define PRE 24      // prefetch fast path (max Poisson(8) count over 2048 classes ~22)
#define BT 512      // threads per block (8 waves)

typedef __attribute__((ext_vector_type(8))) short short8v;
typedef __attribute__((ext_vector_type(4))) float float4v;

static __device__ __forceinline__ unsigned short f2bf(float f) {
    union { __hip_bfloat16 h; unsigned short u; } cv;
    cv.h = __float2bfloat16(f);
    return cv.u;
}

// grid barrier: monotonic counter (zeroed by memset node each replay).
// arrive = one RMW per block; poll = device-scope PLAIN LOAD + sleep backoff
// (round-5's RMW-poll storm was the 130us failure; loads don't take ownership).
static __device__ __forceinline__ void gbar(int* ctr, int nblk) {
    __syncthreads();
    if (threadIdx.x == 0) {
        __threadfence();                   // release prior writes to device scope
        atomicAdd(ctr, 1);
        while (__hip_atomic_load(ctr, __ATOMIC_RELAXED, __HIP_MEMORY_SCOPE_AGENT) < nblk)
            __builtin_amdgcn_s_sleep(16);  // ~1024 cycles between polls
        __threadfence();                   // acquire
    }
    __syncthreads();
}

__global__ void __launch_bounds__(BT, 4)
k_fused(const float* __restrict__ x, const float* __restrict__ kw,
        const float* __restrict__ p_in, const int* __restrict__ tgt,
        unsigned short* __restrict__ qb, float* __restrict__ w,
        int* __restrict__ cnt, int* __restrict__ list2d, int* __restrict__ bar,
        float* __restrict__ part, int* __restrict__ done, float* __restrict__ out,
        int N, int C, float dval, int nblk)
{
    int tid = threadIdx.x, b = blockIdx.x;
    int lane = tid & 63, wv = tid >> 6;

    // ======== P0: bucket-scatter this block's 32 samples ========
    if (tid < 32) {
        int i = b * 32 + tid;
        int t = tgt[i];
        int pos = atomicAdd(&cnt[t], 1);
        if (pos < CAP) list2d[t * CAP + pos] = i;   // unordered; P1 sorts
    }
    gbar(&bar[0], nblk);

    // ======== P1: per-class sequential EMA chain -> qb (kappa folded), w ========
    // waves 0-3 of each block own classes b*4+wv (balanced across all CUs)
    if (wv < 4) {
        int c = b * 4 + wv;                // covers [0, 2048) exactly
        if (c < C) {
            int e = lane & 31;             // lanes 32-63 mirror 0-31
            float p = p_in[(size_t)c * D + e];
            int count = cnt[c];
            if (count <= PRE) {
                // rank-sort indices in-wave, prefetch, ILP-normalize, ALU-only chain
                int idx = (lane < count) ? list2d[c * CAP + lane] : 0x7fffffff;
                int rank = 0;
                for (int j = 0; j < count; ++j) {
                    int v = __shfl(idx, j);
                    rank += (v < idx) ? 1 : 0;
                }
                int sorted = 0;
                for (int j = 0; j < count; ++j) {
                    int v = __shfl(idx, j); int r = __shfl(rank, j);
                    if (r == lane) sorted = v;
                }
                float vals[PRE];
#pragma unroll
                for (int it = 0; it < PRE; ++it)
                    if (it < count) {
                        int si = __shfl(sorted, it);
                        vals[it] = x[(size_t)si * D + e];      // independent loads
                    }
#pragma unroll
                for (int it = 0; it < PRE; ++it)
                    if (it < count) {                           // independent normalizes
                        float v = vals[it];
                        float ss = v * v;
                        ss += __shfl_xor(ss, 16); ss += __shfl_xor(ss, 8); ss += __shfl_xor(ss, 4);
                        ss += __shfl_xor(ss, 2);  ss += __shfl_xor(ss, 1);
                        vals[it] = v / fmaxf(sqrtf(ss), 1e-12f);
                    }
#pragma unroll
                for (int it = 0; it < PRE; ++it)
                    if (it < count) {                           // sequential EMA chain
                        p = fmaf(0.05f, vals[it], 0.95f * p);
                        float pp = p * p;
                        pp += __shfl_xor(pp, 16); pp += __shfl_xor(pp, 8); pp += __shfl_xor(pp, 4);
                        pp += __shfl_xor(pp, 2);  pp += __shfl_xor(pp, 1);
                        p = p / fmaxf(sqrtf(pp), 1e-12f);
                    }
            } else if (count <= CAP) {
                // exact mid path: min-extract ordered chain
                int idx = (lane < count) ? list2d[c * CAP + lane] : 0x7fffffff;
                for (int it = 0; it < count; ++it) {
                    int mn = idx;
                    mn = min(mn, __shfl_xor(mn, 32)); mn = min(mn, __shfl_xor(mn, 16));
                    mn = min(mn, __shfl_xor(mn, 8));  mn = min(mn, __shfl_xor(mn, 4));
                    mn = min(mn, __shfl_xor(mn, 2));  mn = min(mn, __shfl_xor(mn, 1));
                    float v = x[(size_t)mn * D + e];
                    float ss = v * v;
                    ss += __shfl_xor(ss, 16); ss += __shfl_xor(ss, 8); ss += __shfl_xor(ss, 4);
                    ss += __shfl_xor(ss, 2);  ss += __shfl_xor(ss, 1);
                    float s = v / fmaxf(sqrtf(ss), 1e-12f);
                    p = fmaf(0.05f, s, 0.95f * p);
                    float pp = p * p;
                    pp += __shfl_xor(pp, 16); pp += __shfl_xor(pp, 8); pp += __shfl_xor(pp, 4);
                    pp += __shfl_xor(pp, 2);  pp += __shfl_xor(pp, 1);
                    p = p / fmaxf(sqrtf(pp), 1e-12f);
                    if (idx == mn) idx = 0x7fffffff;
                }
            } else {
                // exact fallback: full ballot scan (statistically never at N/C=8)
                for (int ii = 0; ii < N; ii += 64) {
                    unsigned long long m = __ballot(tgt[ii + lane] == c);
                    while (m) {
                        int j = __ffsll(m) - 1;
                        m &= (m - 1);
                        float v = x[(size_t)(ii + j) * D + e];
                        float ss = v * v;
                        ss += __shfl_xor(ss, 16); ss += __shfl_xor(ss, 8); ss += __shfl_xor(ss, 4);
                        ss += __shfl_xor(ss, 2);  ss += __shfl_xor(ss, 1);
                        float s = v / fmaxf(sqrtf(ss), 1e-12f);
                        p = fmaf(0.05f, s, 0.95f * p);
                        float pp = p * p;
                        pp += __shfl_xor(pp, 16); pp += __shfl_xor(pp, 8); pp += __shfl_xor(pp, 4);
                        pp += __shfl_xor(pp, 2);  pp += __shfl_xor(pp, 1);
                        p = p / fmaxf(sqrtf(pp), 1e-12f);
                    }
                }
            }
            float pp = p * p;
            pp += __shfl_xor(pp, 16); pp += __shfl_xor(pp, 8); pp += __shfl_xor(pp, 4);
            pp += __shfl_xor(pp, 2);  pp += __shfl_xor(pp, 1);
            float pn = p / fmaxf(sqrtf(pp), 1e-8f);
            float kap = fmaxf(kw[c], 0.0f);
            if (lane < D) qb[(size_t)c * D + e] = f2bf(kap * pn);
            if (lane == 0) {
                // log C_d(kap), cancellation-free rearrangement
                float nu = 0.5f * dval - 1.0f;
                float z  = kap / nu, z2 = z * z;
                float sq = sqrtf(1.0f + z2);
                float t  = 1.0f / sq;
                float u1 = (3.0f * t - 5.0f * t * t * t) * (1.0f / 24.0f);
                float lw = dval * (-0.918938533204672742f)
                         + nu * (logf(nu) + log1pf(sq) - sq)
                         + 0.5f * logf(6.2831853071795864f * nu)
                         + 0.25f * log1pf(z2)
                         - log1pf(u1 / nu);
                w[c] = __expf(lw);
            }
        }
    }
    gbar(&bar[1], nblk);

    // ======== P2: full-row MFMA + exp rowsum + target-logit capture + NLL ========
    __shared__ float Sl[8][32];
    __shared__ float Lt[32];
    __shared__ float redp[8];
    __shared__ int lastflag;
    {
        int m = lane & 15, kg = lane >> 4, k0 = kg * 8;
        int s0 = b * 32;

        // normalized bf16 A fragments straight from x (cos eps 1e-8)
        short8v a0, a1;
        {
            const float4* px = (const float4*)(x + (size_t)(s0 + m) * D + k0);
            float4 u0 = px[0], u1 = px[1];
            float ss = u0.x*u0.x + u0.y*u0.y + u0.z*u0.z + u0.w*u0.w
                     + u1.x*u1.x + u1.y*u1.y + u1.z*u1.z + u1.w*u1.w;
            ss += __shfl_xor(ss, 16); ss += __shfl_xor(ss, 32);
            float inv = 1.0f / fmaxf(sqrtf(ss), 1e-8f);
            a0[0] = (short)f2bf(u0.x*inv); a0[1] = (short)f2bf(u0.y*inv);
            a0[2] = (short)f2bf(u0.z*inv); a0[3] = (short)f2bf(u0.w*inv);
            a0[4] = (short)f2bf(u1.x*inv); a0[5] = (short)f2bf(u1.y*inv);
            a0[6] = (short)f2bf(u1.z*inv); a0[7] = (short)f2bf(u1.w*inv);
        }
        {
            const float4* px = (const float4*)(x + (size_t)(s0 + 16 + m) * D + k0);
            float4 u0 = px[0], u1 = px[1];
            float ss = u0.x*u0.x + u0.y*u0.y + u0.z*u0.z + u0.w*u0.w
                     + u1.x*u1.x + u1.y*u1.y + u1.z*u1.z + u1.w*u1.w;
            ss += __shfl_xor(ss, 16); ss += __shfl_xor(ss, 32);
            float inv = 1.0f / fmaxf(sqrtf(ss), 1e-8f);
            a1[0] = (short)f2bf(u0.x*inv); a1[1] = (short)f2bf(u0.y*inv);
            a1[2] = (short)f2bf(u0.z*inv); a1[3] = (short)f2bf(u0.w*inv);
            a1[4] = (short)f2bf(u1.x*inv); a1[5] = (short)f2bf(u1.y*inv);
            a1[6] = (short)f2bf(u1.z*inv); a1[7] = (short)f2bf(u1.w*inv);
        }

        int tr0[4], tr1[4];
#pragma unroll
        for (int r = 0; r < 4; ++r) {
            tr0[r] = tgt[s0 + kg * 4 + r];
            tr1[r] = tgt[s0 + 16 + kg * 4 + r];
        }

        float4v z = {0.f, 0.f, 0.f, 0.f};
        float4v sa0 = z, sa1 = z;
        int ntiles = C / (16 * 8);             // 16 class-tiles per wave
        for (int jt = 0; jt < ntiles; ++jt) {
            int c0 = (wv * ntiles + jt) * 16;
            short8v bfrag = *(const short8v*)(qb + (size_t)(c0 + m) * D + k0);
            float wl = w[c0 + m];
            float4v acc0 = __builtin_amdgcn_mfma_f32_16x16x32_bf16(a0, bfrag, z, 0, 0, 0);
            float4v acc1 = __builtin_amdgcn_mfma_f32_16x16x32_bf16(a1, bfrag, z, 0, 0, 0);
#pragma unroll
            for (int r = 0; r < 4; ++r) {
                if (c0 + m == tr0[r]) Lt[kg * 4 + r] = acc0[r];        // target logit
                if (c0 + m == tr1[r]) Lt[16 + kg * 4 + r] = acc1[r];
                sa0[r] = fmaf(wl, __expf(acc0[r]), sa0[r]);
                sa1[r] = fmaf(wl, __expf(acc1[r]), sa1[r]);
            }
        }
#pragma unroll
        for (int off = 1; off < 16; off <<= 1) {
#pragma unroll
            for (int r = 0; r < 4; ++r) {
                sa0[r] += __shfl_xor(sa0[r], off);
                sa1[r] += __shfl_xor(sa1[r], off);
            }
        }
        if (m == 0) {
#pragma unroll
            for (int r = 0; r < 4; ++r) {
                Sl[wv][kg * 4 + r]      = sa0[r];
                Sl[wv][16 + kg * 4 + r] = sa1[r];
            }
        }
    }
    __syncthreads();

    // per-sample NLL (wave 0, lanes 0-31) + block partial
    float val = 0.f;
    if (wv == 0) {
        if (lane < 32) {
            int s = lane;
            float S = ((Sl[0][s] + Sl[1][s]) + (Sl[2][s] + Sl[3][s]))
                    + ((Sl[4][s] + Sl[5][s]) + (Sl[6][s] + Sl[7][s]));
            int t = tgt[b * 32 + s];
            val = logf(w[t] * __expf(Lt[s]) / S + 1e-6f);
        }
        val += __shfl_xor(val, 32); val += __shfl_xor(val, 16); val += __shfl_xor(val, 8);
        val += __shfl_xor(val, 4);  val += __shfl_xor(val, 2);  val += __shfl_xor(val, 1);
    }
    if (tid == 0) {
        atomicExch((unsigned int*)&part[b], __float_as_uint(val));  // coherent publish
        __threadfence();
        int old = atomicAdd(done, 1);
        lastflag = (old == nblk - 1) ? 1 : 0;
    }
    __syncthreads();

    // last block: deterministic fixed-order final reduce
    if (lastflag) {
        __threadfence();
        float v = (tid < nblk) ? __uint_as_float(
            __hip_atomic_load((unsigned int*)&part[tid], __ATOMIC_RELAXED,
                              __HIP_MEMORY_SCOPE_AGENT)) : 0.f;
        v += __shfl_xor(v, 32); v += __shfl_xor(v, 16); v += __shfl_xor(v, 8);
        v += __shfl_xor(v, 4);  v += __shfl_xor(v, 2);  v += __shfl_xor(v, 1);
        if (lane == 0) redp[wv] = v;
        __syncthreads();
        if (tid == 0)
            out[0] = -(((redp[0] + redp[1]) + (redp[2] + redp[3]))
                     + ((redp[4] + redp[5]) + (redp[6] + redp[7]))) / (float)N;
    }
}

extern "C" void kernel_launch(void* const* d_in, const int* in_sizes, int n_in,
                              void* d_out, int out_size, void* d_ws, size_t ws_size,
                              hipStream_t stream) {
    const float* x    = (const float*)d_in[0];   // [N, D]
    const float* kw   = (const float*)d_in[1];   // [C]
    const float* p_in = (const float*)d_in[2];   // [C, D]
    const int*   tgt  = (const int*)d_in[3];     // [N]
    int C = in_sizes[1];
    int N = in_sizes[3];
    float dval = (float)(in_sizes[2] / C);       // == 32
    int nblk = N / 32;                            // 512 blocks, 2/CU co-resident

    // ws layout: [zero region: cnt C | done 1 | bar 2 | pad to 64B] qb | w | part | list2d
    int* cnt  = (int*)d_ws;
    int* done = cnt + C;
    int* bar  = done + 1;
    size_t zbytes = ((size_t)(C + 16) * sizeof(int) + 63) & ~(size_t)63;
    unsigned short* qb = (unsigned short*)((char*)d_ws + zbytes);   // C*D bf16
    float* w    = (float*)(qb + (size_t)C * D);                     // C f32
    float* part = w + C;                                            // nblk f32
    int* list2d = (int*)(part + nblk);                              // C*CAP ints
    (void)n_in; (void)out_size; (void)ws_size;

    // node 1: zero cnt/done/bar (re-zeroed every graph replay)
    hipMemsetAsync(d_ws, 0, (size_t)(C + 16) * sizeof(int), stream);
    // node 2: fully fused pipeline
    k_fused<<<nblk, BT, 0, stream>>>(x, kw, p_in, tgt, qb, w, cnt, list2d,
                                     bar, part, done, (float*)d_out, N, C, dval, nblk);
}

// Round 8
// 44.136 us; speedup vs baseline: 3.0233x; 3.0233x over previous
//
#include <hip/hip_runtime.h>
#include <hip/hip_bf16.h>
#include <math.h>

#define D 32
#define CAP 64      // bucket capacity (mid path up to CAP, full-scan beyond)
#define PRE 24      // prefetch fast path (max Poisson(8) count over 2048 classes ~22)
#define SBT 512     // k_score threads (8 waves)

typedef __attribute__((ext_vector_type(8))) short short8v;
typedef __attribute__((ext_vector_type(4))) float float4v;

static __device__ __forceinline__ unsigned short f2bf(float f) {
    union { __hip_bfloat16 h; unsigned short u; } cv;
    cv.h = __float2bfloat16(f);
    return cv.u;
}

// ---- K1: bucket-scatter sample indices by class (unordered; k_proto sorts) ----
__global__ void k_bucket(const int* __restrict__ tgt, int* __restrict__ cnt,
                         int* __restrict__ list2d, int N) {
    int i = blockIdx.x * blockDim.x + threadIdx.x;
    if (i < N) {
        int t = tgt[i];
        int pos = atomicAdd(&cnt[t], 1);
        if (pos < CAP) list2d[t * CAP + pos] = i;
    }
}

// ---- K2: per-class sequential EMA chain -> qb (bf16, kappa folded), w ----
__global__ void k_proto(const float* __restrict__ x, const int* __restrict__ tgt,
                        const int* __restrict__ list2d, const int* __restrict__ cnt,
                        const float* __restrict__ p_in, const float* __restrict__ kw,
                        unsigned short* __restrict__ qb, float* __restrict__ w,
                        int N, int C, float dval) {
    int wave = (blockIdx.x * blockDim.x + threadIdx.x) >> 6;
    int lane = threadIdx.x & 63;
    if (wave >= C) return;
    int c = wave, e = lane & 31;           // lanes 32-63 mirror 0-31
    float p = p_in[(size_t)c * D + e];
    int count = cnt[c];

    if (count <= PRE) {
        // rank-sort indices in-wave, prefetch, ILP-normalize, ALU-only chain
        int idx = (lane < count) ? list2d[c * CAP + lane] : 0x7fffffff;
        int rank = 0;
        for (int j = 0; j < count; ++j) {
            int v = __shfl(idx, j);
            rank += (v < idx) ? 1 : 0;
        }
        int sorted = 0;
        for (int j = 0; j < count; ++j) {
            int v = __shfl(idx, j); int r = __shfl(rank, j);
            if (r == lane) sorted = v;
        }
        float vals[PRE];
#pragma unroll
        for (int it = 0; it < PRE; ++it)
            if (it < count) {
                int si = __shfl(sorted, it);
                vals[it] = x[(size_t)si * D + e];      // independent loads
            }
#pragma unroll
        for (int it = 0; it < PRE; ++it)
            if (it < count) {                           // independent normalizes
                float v = vals[it];
                float ss = v * v;
                ss += __shfl_xor(ss, 16); ss += __shfl_xor(ss, 8); ss += __shfl_xor(ss, 4);
                ss += __shfl_xor(ss, 2);  ss += __shfl_xor(ss, 1);
                vals[it] = v / fmaxf(sqrtf(ss), 1e-12f);
            }
#pragma unroll
        for (int it = 0; it < PRE; ++it)
            if (it < count) {                           // sequential EMA chain
                p = fmaf(0.05f, vals[it], 0.95f * p);
                float pp = p * p;
                pp += __shfl_xor(pp, 16); pp += __shfl_xor(pp, 8); pp += __shfl_xor(pp, 4);
                pp += __shfl_xor(pp, 2);  pp += __shfl_xor(pp, 1);
                p = p / fmaxf(sqrtf(pp), 1e-12f);
            }
    } else if (count <= CAP) {
        // exact mid path: min-extract ordered chain
        int idx = (lane < count) ? list2d[c * CAP + lane] : 0x7fffffff;
        for (int it = 0; it < count; ++it) {
            int mn = idx;
            mn = min(mn, __shfl_xor(mn, 32)); mn = min(mn, __shfl_xor(mn, 16));
            mn = min(mn, __shfl_xor(mn, 8));  mn = min(mn, __shfl_xor(mn, 4));
            mn = min(mn, __shfl_xor(mn, 2));  mn = min(mn, __shfl_xor(mn, 1));
            float v = x[(size_t)mn * D + e];
            float ss = v * v;
            ss += __shfl_xor(ss, 16); ss += __shfl_xor(ss, 8); ss += __shfl_xor(ss, 4);
            ss += __shfl_xor(ss, 2);  ss += __shfl_xor(ss, 1);
            float s = v / fmaxf(sqrtf(ss), 1e-12f);
            p = fmaf(0.05f, s, 0.95f * p);
            float pp = p * p;
            pp += __shfl_xor(pp, 16); pp += __shfl_xor(pp, 8); pp += __shfl_xor(pp, 4);
            pp += __shfl_xor(pp, 2);  pp += __shfl_xor(pp, 1);
            p = p / fmaxf(sqrtf(pp), 1e-12f);
            if (idx == mn) idx = 0x7fffffff;
        }
    } else {
        // exact fallback: full ballot scan (statistically never at N/C=8)
        for (int ii = 0; ii < N; ii += 64) {
            unsigned long long m = __ballot(tgt[ii + lane] == c);
            while (m) {
                int j = __ffsll(m) - 1;
                m &= (m - 1);
                float v = x[(size_t)(ii + j) * D + e];
                float ss = v * v;
                ss += __shfl_xor(ss, 16); ss += __shfl_xor(ss, 8); ss += __shfl_xor(ss, 4);
                ss += __shfl_xor(ss, 2);  ss += __shfl_xor(ss, 1);
                float s = v / fmaxf(sqrtf(ss), 1e-12f);
                p = fmaf(0.05f, s, 0.95f * p);
                float pp = p * p;
                pp += __shfl_xor(pp, 16); pp += __shfl_xor(pp, 8); pp += __shfl_xor(pp, 4);
                pp += __shfl_xor(pp, 2);  pp += __shfl_xor(pp, 1);
                p = p / fmaxf(sqrtf(pp), 1e-12f);
            }
        }
    }

    float pp = p * p;
    pp += __shfl_xor(pp, 16); pp += __shfl_xor(pp, 8); pp += __shfl_xor(pp, 4);
    pp += __shfl_xor(pp, 2);  pp += __shfl_xor(pp, 1);
    float pn = p / fmaxf(sqrtf(pp), 1e-8f);
    float kap = fmaxf(kw[c], 0.0f);
    if (lane < D) qb[(size_t)c * D + e] = f2bf(kap * pn);
    if (lane == 0) {
        // log C_d(kap), cancellation-free rearrangement
        float nu = 0.5f * dval - 1.0f;
        float z  = kap / nu, z2 = z * z;
        float sq = sqrtf(1.0f + z2);
        float t  = 1.0f / sq;
        float u1 = (3.0f * t - 5.0f * t * t * t) * (1.0f / 24.0f);
        float lw = dval * (-0.918938533204672742f)
                 + nu * (logf(nu) + log1pf(sq) - sq)
                 + 0.5f * logf(6.2831853071795864f * nu)
                 + 0.25f * log1pf(z2)
                 - log1pf(u1 / nu);
        w[c] = __expf(lw);
    }
}

// ---- K3: per-block full-row MFMA + exp rowsum + target-logit capture + NLL ----
// 512 blocks x 8 waves; block owns 32 samples; wave wv owns classes [wv*256,(wv+1)*256).
// NO fences, NO atomics: block partial leaves via one plain store.
__global__ void __launch_bounds__(SBT)
k_score(const float* __restrict__ x, const int* __restrict__ tgt,
        const unsigned short* __restrict__ qb, const float* __restrict__ w,
        float* __restrict__ part, int N, int C) {
    __shared__ float Sl[8][32];
    __shared__ float Lt[32];
    int tid = threadIdx.x, b = blockIdx.x;
    int lane = tid & 63, wv = tid >> 6;
    int m = lane & 15, kg = lane >> 4, k0 = kg * 8;
    int s0 = b * 32;

    // normalized bf16 A fragments straight from x (cos eps 1e-8)
    short8v a0, a1;
    {
        const float4* px = (const float4*)(x + (size_t)(s0 + m) * D + k0);
        float4 u0 = px[0], u1 = px[1];
        float ss = u0.x*u0.x + u0.y*u0.y + u0.z*u0.z + u0.w*u0.w
                 + u1.x*u1.x + u1.y*u1.y + u1.z*u1.z + u1.w*u1.w;
        ss += __shfl_xor(ss, 16); ss += __shfl_xor(ss, 32);
        float inv = 1.0f / fmaxf(sqrtf(ss), 1e-8f);
        a0[0] = (short)f2bf(u0.x*inv); a0[1] = (short)f2bf(u0.y*inv);
        a0[2] = (short)f2bf(u0.z*inv); a0[3] = (short)f2bf(u0.w*inv);
        a0[4] = (short)f2bf(u1.x*inv); a0[5] = (short)f2bf(u1.y*inv);
        a0[6] = (short)f2bf(u1.z*inv); a0[7] = (short)f2bf(u1.w*inv);
    }
    {
        const float4* px = (const float4*)(x + (size_t)(s0 + 16 + m) * D + k0);
        float4 u0 = px[0], u1 = px[1];
        float ss = u0.x*u0.x + u0.y*u0.y + u0.z*u0.z + u0.w*u0.w
                 + u1.x*u1.x + u1.y*u1.y + u1.z*u1.z + u1.w*u1.w;
        ss += __shfl_xor(ss, 16); ss += __shfl_xor(ss, 32);
        float inv = 1.0f / fmaxf(sqrtf(ss), 1e-8f);
        a1[0] = (short)f2bf(u0.x*inv); a1[1] = (short)f2bf(u0.y*inv);
        a1[2] = (short)f2bf(u0.z*inv); a1[3] = (short)f2bf(u0.w*inv);
        a1[4] = (short)f2bf(u1.x*inv); a1[5] = (short)f2bf(u1.y*inv);
        a1[6] = (short)f2bf(u1.z*inv); a1[7] = (short)f2bf(u1.w*inv);
    }

    int tr0[4], tr1[4];
#pragma unroll
    for (int r = 0; r < 4; ++r) {
        tr0[r] = tgt[s0 + kg * 4 + r];
        tr1[r] = tgt[s0 + 16 + kg * 4 + r];
    }

    float4v z = {0.f, 0.f, 0.f, 0.f};
    float4v sa0 = z, sa1 = z;
    int ntiles = C / (16 * 8);             // 16 class-tiles per wave
    for (int jt = 0; jt < ntiles; ++jt) {
        int c0 = (wv * ntiles + jt) * 16;
        short8v bfrag = *(const short8v*)(qb + (size_t)(c0 + m) * D + k0);
        float wl = w[c0 + m];
        float4v acc0 = __builtin_amdgcn_mfma_f32_16x16x32_bf16(a0, bfrag, z, 0, 0, 0);
        float4v acc1 = __builtin_amdgcn_mfma_f32_16x16x32_bf16(a1, bfrag, z, 0, 0, 0);
#pragma unroll
        for (int r = 0; r < 4; ++r) {
            if (c0 + m == tr0[r]) Lt[kg * 4 + r] = acc0[r];        // target logit
            if (c0 + m == tr1[r]) Lt[16 + kg * 4 + r] = acc1[r];
            sa0[r] = fmaf(wl, __expf(acc0[r]), sa0[r]);
            sa1[r] = fmaf(wl, __expf(acc1[r]), sa1[r]);
        }
    }
#pragma unroll
    for (int off = 1; off < 16; off <<= 1) {
#pragma unroll
        for (int r = 0; r < 4; ++r) {
            sa0[r] += __shfl_xor(sa0[r], off);
            sa1[r] += __shfl_xor(sa1[r], off);
        }
    }
    if (m == 0) {
#pragma unroll
        for (int r = 0; r < 4; ++r) {
            Sl[wv][kg * 4 + r]      = sa0[r];
            Sl[wv][16 + kg * 4 + r] = sa1[r];
        }
    }
    __syncthreads();

    // per-sample NLL (wave 0, lanes 0-31) + one plain-store block partial
    if (wv == 0) {
        float val = 0.f;
        if (lane < 32) {
            int s = lane;
            float S = ((Sl[0][s] + Sl[1][s]) + (Sl[2][s] + Sl[3][s]))
                    + ((Sl[4][s] + Sl[5][s]) + (Sl[6][s] + Sl[7][s]));
            int t = tgt[s0 + s];
            val = logf(w[t] * __expf(Lt[s]) / S + 1e-6f);
        }
        val += __shfl_xor(val, 32); val += __shfl_xor(val, 16); val += __shfl_xor(val, 8);
        val += __shfl_xor(val, 4);  val += __shfl_xor(val, 2);  val += __shfl_xor(val, 1);
        if (lane == 0) part[b] = val;
    }
}

// ---- K4: deterministic fixed-order final reduce (1 block) ----
__global__ void k_out(const float* __restrict__ part, float* __restrict__ out,
                      int N, int nblk) {
    __shared__ float red[8];
    int tid = threadIdx.x, lane = tid & 63, wv = tid >> 6;
    float v = (tid < nblk) ? part[tid] : 0.f;
    v += __shfl_xor(v, 32); v += __shfl_xor(v, 16); v += __shfl_xor(v, 8);
    v += __shfl_xor(v, 4);  v += __shfl_xor(v, 2);  v += __shfl_xor(v, 1);
    if (lane == 0) red[wv] = v;
    __syncthreads();
    if (tid == 0)
        out[0] = -(((red[0] + red[1]) + (red[2] + red[3]))
                 + ((red[4] + red[5]) + (red[6] + red[7]))) / (float)N;
}

extern "C" void kernel_launch(void* const* d_in, const int* in_sizes, int n_in,
                              void* d_out, int out_size, void* d_ws, size_t ws_size,
                              hipStream_t stream) {
    const float* x    = (const float*)d_in[0];   // [N, D]
    const float* kw   = (const float*)d_in[1];   // [C]
    const float* p_in = (const float*)d_in[2];   // [C, D]
    const int*   tgt  = (const int*)d_in[3];     // [N]
    int C = in_sizes[1];
    int N = in_sizes[3];
    float dval = (float)(in_sizes[2] / C);       // == 32
    int nblk = N / 32;                            // 512 score blocks

    // ws layout: [cnt C (zeroed)] | qb | w | part | list2d
    int* cnt = (int*)d_ws;
    size_t zbytes = ((size_t)C * sizeof(int) + 63) & ~(size_t)63;
    unsigned short* qb = (unsigned short*)((char*)d_ws + zbytes);   // C*D bf16
    float* w    = (float*)(qb + (size_t)C * D);                     // C f32
    float* part = w + C;                                            // nblk f32
    int* list2d = (int*)(part + nblk);                              // C*CAP ints
    (void)n_in; (void)out_size; (void)ws_size;

    // node 1: zero cnt (runs every replay)
    hipMemsetAsync(cnt, 0, (size_t)C * sizeof(int), stream);
    // node 2: bucket-scatter
    k_bucket<<<(N + 255) / 256, 256, 0, stream>>>(tgt, cnt, list2d, N);
    // node 3: per-class EMA chains -> qb, w
    k_proto<<<(C * 64 + 255) / 256, 256, 0, stream>>>(x, tgt, list2d, cnt, p_in, kw, qb, w, N, C, dval);
    // node 4: full-row score + NLL partials (fence-free)
    k_score<<<nblk, SBT, 0, stream>>>(x, tgt, qb, w, part, N, C);
    // node 5: final reduce
    k_out<<<1, 512, 0, stream>>>(part, (float*)d_out, N, nblk);
}

// Round 9
// 40.515 us; speedup vs baseline: 3.2936x; 1.0894x over previous
//
#include <hip/hip_runtime.h>
#include <hip/hip_bf16.h>
#include <math.h>

#define D 32
#define CAP 64      // per-class LDS list capacity (fallback to full scan beyond)
#define PRE 24      // prefetch fast path (max Poisson(8) count over 2048 classes ~22)
#define PBW 8       // classes (=waves) per k_pb block
#define SBT 512     // k_score threads (8 waves)

typedef __attribute__((ext_vector_type(8))) short short8v;
typedef __attribute__((ext_vector_type(4))) float float4v;

static __device__ __forceinline__ unsigned short f2bf(float f) {
    union { __hip_bfloat16 h; unsigned short u; } cv;
    cv.h = __float2bfloat16(f);
    return cv.u;
}

// ---- K1: fused bucket (LDS, block-local) + per-class sequential EMA chain ----
// 256 blocks x 512 threads; block owns classes [b*8, b*8+8), wave wv owns class b*8+wv.
// No global scratch consumed -> no memset node, no global atomics.
__global__ void __launch_bounds__(64 * PBW)
k_pb(const float* __restrict__ x, const int* __restrict__ tgt,
     const float* __restrict__ p_in, const float* __restrict__ kw,
     unsigned short* __restrict__ qb, float* __restrict__ w,
     int N, int C, float dval) {
    __shared__ int lcnt[PBW];
    __shared__ int llist[PBW][CAP];
    int tid = threadIdx.x, b = blockIdx.x;
    int lane = tid & 63, wv = tid >> 6;
    int c0 = b * PBW;

    // Phase A: block scans full tgt, scatters its classes' sample indices into LDS
    if (tid < PBW) lcnt[tid] = 0;
    __syncthreads();
    for (int i = tid; i < N; i += 64 * PBW) {        // 32 coalesced iters
        int t = tgt[i];
        int r = t - c0;
        if ((unsigned)r < (unsigned)PBW) {
            int pos = atomicAdd(&lcnt[r], 1);        // LDS atomic
            if (pos < CAP) llist[r][pos] = i;        // unordered; sorted below
        }
    }
    __syncthreads();

    // Phase B: wave wv runs the exact sequential EMA chain for class c0+wv
    int c = c0 + wv;
    int e = lane & 31;                 // lanes 32-63 mirror 0-31
    float p = p_in[(size_t)c * D + e];
    int count = lcnt[wv];

    if (count <= PRE) {
        // rank-sort indices in-wave, prefetch, ILP-normalize, ALU-only chain
        int idx = (lane < count) ? llist[wv][lane] : 0x7fffffff;
        int rank = 0;
        for (int j = 0; j < count; ++j) {
            int v = __shfl(idx, j);
            rank += (v < idx) ? 1 : 0;
        }
        int sorted = 0;
        for (int j = 0; j < count; ++j) {
            int v = __shfl(idx, j); int r = __shfl(rank, j);
            if (r == lane) sorted = v;
        }
        float vals[PRE];
#pragma unroll
        for (int it = 0; it < PRE; ++it)
            if (it < count) {
                int si = __shfl(sorted, it);
                vals[it] = x[(size_t)si * D + e];      // independent loads
            }
#pragma unroll
        for (int it = 0; it < PRE; ++it)
            if (it < count) {                           // independent normalizes
                float v = vals[it];
                float ss = v * v;
                ss += __shfl_xor(ss, 16); ss += __shfl_xor(ss, 8); ss += __shfl_xor(ss, 4);
                ss += __shfl_xor(ss, 2);  ss += __shfl_xor(ss, 1);
                vals[it] = v / fmaxf(sqrtf(ss), 1e-12f);
            }
#pragma unroll
        for (int it = 0; it < PRE; ++it)
            if (it < count) {                           // sequential EMA chain
                p = fmaf(0.05f, vals[it], 0.95f * p);
                float pp = p * p;
                pp += __shfl_xor(pp, 16); pp += __shfl_xor(pp, 8); pp += __shfl_xor(pp, 4);
                pp += __shfl_xor(pp, 2);  pp += __shfl_xor(pp, 1);
                p = p / fmaxf(sqrtf(pp), 1e-12f);
            }
    } else if (count <= CAP) {
        // exact mid path: min-extract ordered chain
        int idx = (lane < count) ? llist[wv][lane] : 0x7fffffff;
        for (int it = 0; it < count; ++it) {
            int mn = idx;
            mn = min(mn, __shfl_xor(mn, 32)); mn = min(mn, __shfl_xor(mn, 16));
            mn = min(mn, __shfl_xor(mn, 8));  mn = min(mn, __shfl_xor(mn, 4));
            mn = min(mn, __shfl_xor(mn, 2));  mn = min(mn, __shfl_xor(mn, 1));
            float v = x[(size_t)mn * D + e];
            float ss = v * v;
            ss += __shfl_xor(ss, 16); ss += __shfl_xor(ss, 8); ss += __shfl_xor(ss, 4);
            ss += __shfl_xor(ss, 2);  ss += __shfl_xor(ss, 1);
            float s = v / fmaxf(sqrtf(ss), 1e-12f);
            p = fmaf(0.05f, s, 0.95f * p);
            float pp = p * p;
            pp += __shfl_xor(pp, 16); pp += __shfl_xor(pp, 8); pp += __shfl_xor(pp, 4);
            pp += __shfl_xor(pp, 2);  pp += __shfl_xor(pp, 1);
            p = p / fmaxf(sqrtf(pp), 1e-12f);
            if (idx == mn) idx = 0x7fffffff;
        }
    } else {
        // exact fallback: full ballot scan (statistically never at N/C=8)
        for (int ii = 0; ii < N; ii += 64) {
            unsigned long long m = __ballot(tgt[ii + lane] == c);
            while (m) {
                int j = __ffsll(m) - 1;
                m &= (m - 1);
                float v = x[(size_t)(ii + j) * D + e];
                float ss = v * v;
                ss += __shfl_xor(ss, 16); ss += __shfl_xor(ss, 8); ss += __shfl_xor(ss, 4);
                ss += __shfl_xor(ss, 2);  ss += __shfl_xor(ss, 1);
                float s = v / fmaxf(sqrtf(ss), 1e-12f);
                p = fmaf(0.05f, s, 0.95f * p);
                float pp = p * p;
                pp += __shfl_xor(pp, 16); pp += __shfl_xor(pp, 8); pp += __shfl_xor(pp, 4);
                pp += __shfl_xor(pp, 2);  pp += __shfl_xor(pp, 1);
                p = p / fmaxf(sqrtf(pp), 1e-12f);
            }
        }
    }

    float pp = p * p;
    pp += __shfl_xor(pp, 16); pp += __shfl_xor(pp, 8); pp += __shfl_xor(pp, 4);
    pp += __shfl_xor(pp, 2);  pp += __shfl_xor(pp, 1);
    float pn = p / fmaxf(sqrtf(pp), 1e-8f);
    float kap = fmaxf(kw[c], 0.0f);
    if (lane < D) qb[(size_t)c * D + e] = f2bf(kap * pn);
    if (lane == 0) {
        // log C_d(kap), cancellation-free rearrangement
        float nu = 0.5f * dval - 1.0f;
        float z  = kap / nu, z2 = z * z;
        float sq = sqrtf(1.0f + z2);
        float t  = 1.0f / sq;
        float u1 = (3.0f * t - 5.0f * t * t * t) * (1.0f / 24.0f);
        float lw = dval * (-0.918938533204672742f)
                 + nu * (logf(nu) + log1pf(sq) - sq)
                 + 0.5f * logf(6.2831853071795864f * nu)
                 + 0.25f * log1pf(z2)
                 - log1pf(u1 / nu);
        w[c] = __expf(lw);
    }
}

// ---- K2: per-block full-row MFMA + exp rowsum + target-logit capture + NLL ----
// 512 blocks x 8 waves; block owns 32 samples; wave wv owns classes [wv*256,(wv+1)*256).
// Fence-free: block partial leaves via one plain store.
__global__ void __launch_bounds__(SBT)
k_score(const float* __restrict__ x, const int* __restrict__ tgt,
        const unsigned short* __restrict__ qb, const float* __restrict__ w,
        float* __restrict__ part, int N, int C) {
    __shared__ float Sl[8][32];
    __shared__ float Lt[32];
    int tid = threadIdx.x, b = blockIdx.x;
    int lane = tid & 63, wv = tid >> 6;
    int m = lane & 15, kg = lane >> 4, k0 = kg * 8;
    int s0 = b * 32;

    // normalized bf16 A fragments straight from x (cos eps 1e-8)
    short8v a0, a1;
    {
        const float4* px = (const float4*)(x + (size_t)(s0 + m) * D + k0);
        float4 u0 = px[0], u1 = px[1];
        float ss = u0.x*u0.x + u0.y*u0.y + u0.z*u0.z + u0.w*u0.w
                 + u1.x*u1.x + u1.y*u1.y + u1.z*u1.z + u1.w*u1.w;
        ss += __shfl_xor(ss, 16); ss += __shfl_xor(ss, 32);
        float inv = 1.0f / fmaxf(sqrtf(ss), 1e-8f);
        a0[0] = (short)f2bf(u0.x*inv); a0[1] = (short)f2bf(u0.y*inv);
        a0[2] = (short)f2bf(u0.z*inv); a0[3] = (short)f2bf(u0.w*inv);
        a0[4] = (short)f2bf(u1.x*inv); a0[5] = (short)f2bf(u1.y*inv);
        a0[6] = (short)f2bf(u1.z*inv); a0[7] = (short)f2bf(u1.w*inv);
    }
    {
        const float4* px = (const float4*)(x + (size_t)(s0 + 16 + m) * D + k0);
        float4 u0 = px[0], u1 = px[1];
        float ss = u0.x*u0.x + u0.y*u0.y + u0.z*u0.z + u0.w*u0.w
                 + u1.x*u1.x + u1.y*u1.y + u1.z*u1.z + u1.w*u1.w;
        ss += __shfl_xor(ss, 16); ss += __shfl_xor(ss, 32);
        float inv = 1.0f / fmaxf(sqrtf(ss), 1e-8f);
        a1[0] = (short)f2bf(u0.x*inv); a1[1] = (short)f2bf(u0.y*inv);
        a1[2] = (short)f2bf(u0.z*inv); a1[3] = (short)f2bf(u0.w*inv);
        a1[4] = (short)f2bf(u1.x*inv); a1[5] = (short)f2bf(u1.y*inv);
        a1[6] = (short)f2bf(u1.z*inv); a1[7] = (short)f2bf(u1.w*inv);
    }

    int tr0[4], tr1[4];
#pragma unroll
    for (int r = 0; r < 4; ++r) {
        tr0[r] = tgt[s0 + kg * 4 + r];
        tr1[r] = tgt[s0 + 16 + kg * 4 + r];
    }

    float4v z = {0.f, 0.f, 0.f, 0.f};
    float4v sa0 = z, sa1 = z;
    int ntiles = C / (16 * 8);             // 16 class-tiles per wave
    for (int jt = 0; jt < ntiles; ++jt) {
        int c0 = (wv * ntiles + jt) * 16;
        short8v bfrag = *(const short8v*)(qb + (size_t)(c0 + m) * D + k0);
        float wl = w[c0 + m];
        float4v acc0 = __builtin_amdgcn_mfma_f32_16x16x32_bf16(a0, bfrag, z, 0, 0, 0);
        float4v acc1 = __builtin_amdgcn_mfma_f32_16x16x32_bf16(a1, bfrag, z, 0, 0, 0);
#pragma unroll
        for (int r = 0; r < 4; ++r) {
            if (c0 + m == tr0[r]) Lt[kg * 4 + r] = acc0[r];        // target logit
            if (c0 + m == tr1[r]) Lt[16 + kg * 4 + r] = acc1[r];
            sa0[r] = fmaf(wl, __expf(acc0[r]), sa0[r]);
            sa1[r] = fmaf(wl, __expf(acc1[r]), sa1[r]);
        }
    }
#pragma unroll
    for (int off = 1; off < 16; off <<= 1) {
#pragma unroll
        for (int r = 0; r < 4; ++r) {
            sa0[r] += __shfl_xor(sa0[r], off);
            sa1[r] += __shfl_xor(sa1[r], off);
        }
    }
    if (m == 0) {
#pragma unroll
        for (int r = 0; r < 4; ++r) {
            Sl[wv][kg * 4 + r]      = sa0[r];
            Sl[wv][16 + kg * 4 + r] = sa1[r];
        }
    }
    __syncthreads();

    // per-sample NLL (wave 0, lanes 0-31) + one plain-store block partial
    if (wv == 0) {
        float val = 0.f;
        if (lane < 32) {
            int s = lane;
            float S = ((Sl[0][s] + Sl[1][s]) + (Sl[2][s] + Sl[3][s]))
                    + ((Sl[4][s] + Sl[5][s]) + (Sl[6][s] + Sl[7][s]));
            int t = tgt[s0 + s];
            val = logf(w[t] * __expf(Lt[s]) / S + 1e-6f);
        }
        val += __shfl_xor(val, 32); val += __shfl_xor(val, 16); val += __shfl_xor(val, 8);
        val += __shfl_xor(val, 4);  val += __shfl_xor(val, 2);  val += __shfl_xor(val, 1);
        if (lane == 0) part[b] = val;
    }
}

// ---- K3: deterministic fixed-order final reduce (1 block) ----
__global__ void k_out(const float* __restrict__ part, float* __restrict__ out,
                      int N, int nblk) {
    __shared__ float red[8];
    int tid = threadIdx.x, lane = tid & 63, wv = tid >> 6;
    float v = (tid < nblk) ? part[tid] : 0.f;
    v += __shfl_xor(v, 32); v += __shfl_xor(v, 16); v += __shfl_xor(v, 8);
    v += __shfl_xor(v, 4);  v += __shfl_xor(v, 2);  v += __shfl_xor(v, 1);
    if (lane == 0) red[wv] = v;
    __syncthreads();
    if (tid == 0)
        out[0] = -(((red[0] + red[1]) + (red[2] + red[3]))
                 + ((red[4] + red[5]) + (red[6] + red[7]))) / (float)N;
}

extern "C" void kernel_launch(void* const* d_in, const int* in_sizes, int n_in,
                              void* d_out, int out_size, void* d_ws, size_t ws_size,
                              hipStream_t stream) {
    const float* x    = (const float*)d_in[0];   // [N, D]
    const float* kw   = (const float*)d_in[1];   // [C]
    const float* p_in = (const float*)d_in[2];   // [C, D]
    const int*   tgt  = (const int*)d_in[3];     // [N]
    int C = in_sizes[1];
    int N = in_sizes[3];
    float dval = (float)(in_sizes[2] / C);       // == 32
    int nblk = N / 32;                            // 512 score blocks

    // ws layout: qb | w | part   (no zero-init region needed)
    unsigned short* qb = (unsigned short*)d_ws;            // C*D bf16
    float* w    = (float*)(qb + (size_t)C * D);            // C f32
    float* part = w + C;                                   // nblk f32
    (void)n_in; (void)out_size; (void)ws_size;

    // node 1: fused LDS-bucket + per-class EMA chains -> qb, w
    k_pb<<<C / PBW, 64 * PBW, 0, stream>>>(x, tgt, p_in, kw, qb, w, N, C, dval);
    // node 2: full-row score + NLL partials (fence-free)
    k_score<<<nblk, SBT, 0, stream>>>(x, tgt, qb, w, part, N, C);
    // node 3: final reduce
    k_out<<<1, 512, 0, stream>>>(part, (float*)d_out, N, nblk);
}